// Round 23
// baseline (1233.930 us; speedup 1.0000x reference)
//
#include <hip/hip_runtime.h>
#include <hip/hip_bf16.h>
#include <math.h>

#define B_    8
#define L_    1024
#define DM_   1024
#define H_    32
#define P_    64
#define NS_   128
#define DI_   2048
#define DXBC_ 2304
#define DINP_ 4384
#define ED_   2048

typedef __attribute__((ext_vector_type(8))) short bf8_t;
typedef __attribute__((ext_vector_type(8))) unsigned short u16x8;
typedef __attribute__((ext_vector_type(4))) float f4_t;

__device__ __forceinline__ float silu_f(float x) { return x / (1.f + __expf(-x)); }

__device__ __forceinline__ unsigned short f2bf(float x) {
    unsigned u = __float_as_uint(x);
    unsigned r = u + 0x7fffu + ((u >> 16) & 1u);   // RNE
    return (unsigned short)(r >> 16);
}
__device__ __forceinline__ float bf2f(unsigned short h) {
    return __uint_as_float(((unsigned)h) << 16);
}
__device__ __forceinline__ float rdlane(float v, int l) {
    return __int_as_float(__builtin_amdgcn_readlane(__float_as_int(v), l));
}

// ---------------- weight conversion: W[K][N] fp32 -> tiled Wt hi/lo bf16 ----------
__global__ __launch_bounds__(256) void convw_k(
    const float* __restrict__ W, unsigned short* __restrict__ hi,
    unsigned short* __restrict__ lo, int K, int N, int Npad)
{
    size_t e = (size_t)blockIdx.x * 256 + threadIdx.x;   // n fastest
    if (e >= (size_t)K * Npad) return;
    int n = (int)(e % Npad), k = (int)(e / Npad);
    float v = (n < N) ? W[(size_t)k * N + n] : 0.f;
    unsigned short h = f2bf(v);
    unsigned short l = f2bf(v - bf2f(h));
    int nt = n >> 7, r = n & 127, kt = k >> 5, c = k & 31;
    size_t dst = ((size_t)(nt * (K >> 5) + kt) << 12) + (r << 5) + c;
    hi[dst] = h; lo[dst] = l;
}

// ------- split-bf16 MFMA GEMM, fused fp32->bf16 A convert, depth-1 pipeline ------
template<bool CHECK_N>
__global__ __launch_bounds__(256, 2) void bgemm_k(
    const float* __restrict__ A, const unsigned short* __restrict__ Whi,
    const unsigned short* __restrict__ Wlo, float* __restrict__ C,
    const float* __restrict__ bias, int M, int N, int K, int ldc)
{
    __shared__ unsigned short Ah[128 * 40], Al[128 * 40];
    __shared__ unsigned short Bh[128 * 40], Bl[128 * 40];
    const int tid = threadIdx.x;
    const int m0 = blockIdx.y * 128, n0 = blockIdx.x * 128;
    const int lane = tid & 63;
    const int wv = tid >> 6;
    const int wr = wv >> 1, wc = wv & 1;
    const int l15 = lane & 15, l4 = lane >> 4;
    const int KT = K >> 5;

    f4_t acc[4][4];
#pragma unroll
    for (int i = 0; i < 4; i++)
#pragma unroll
        for (int j = 0; j < 4; j++) acc[i][j] = (f4_t){0.f, 0.f, 0.f, 0.f};

    const int ar = tid >> 2;
    const int ac = (tid & 3) * 8;
    const int trow = tid >> 1;
    const int tcol = (tid & 1) * 16;
    const int soff = trow * 40 + tcol;

    float4 a00, a01, a10, a11;
    u16x8 rWh0, rWh1, rWl0, rWl1;
#define LOADKT(KTI) {                                                               \
        const float* Ap0 = A + (size_t)(m0 + ar) * K + (KTI) * 32 + ac;             \
        const float* Ap1 = Ap0 + (size_t)64 * K;                                    \
        a00 = *(const float4*)Ap0; a01 = *(const float4*)(Ap0 + 4);                 \
        a10 = *(const float4*)Ap1; a11 = *(const float4*)(Ap1 + 4);                 \
        size_t woff = (((size_t)(blockIdx.x * KT + (KTI))) << 12) + (trow << 5) + tcol; \
        rWh0 = *(const u16x8*)(Whi + woff); rWh1 = *(const u16x8*)(Whi + woff + 8); \
        rWl0 = *(const u16x8*)(Wlo + woff); rWl1 = *(const u16x8*)(Wlo + woff + 8); }

    LOADKT(0);
    for (int kt = 0; kt < KT; ++kt) {
        __syncthreads();
        {
            float av0[8] = {a00.x, a00.y, a00.z, a00.w, a01.x, a01.y, a01.z, a01.w};
            float av1[8] = {a10.x, a10.y, a10.z, a10.w, a11.x, a11.y, a11.z, a11.w};
            u16x8 vh0, vl0, vh1, vl1;
#pragma unroll
            for (int j = 0; j < 8; j++) {
                unsigned short h0 = f2bf(av0[j]);
                vh0[j] = h0; vl0[j] = f2bf(av0[j] - bf2f(h0));
                unsigned short h1 = f2bf(av1[j]);
                vh1[j] = h1; vl1[j] = f2bf(av1[j] - bf2f(h1));
            }
            *(u16x8*)&Ah[ar * 40 + ac] = vh0;
            *(u16x8*)&Al[ar * 40 + ac] = vl0;
            *(u16x8*)&Ah[(ar + 64) * 40 + ac] = vh1;
            *(u16x8*)&Al[(ar + 64) * 40 + ac] = vl1;
            *(u16x8*)&Bh[soff]     = rWh0;
            *(u16x8*)&Bh[soff + 8] = rWh1;
            *(u16x8*)&Bl[soff]     = rWl0;
            *(u16x8*)&Bl[soff + 8] = rWl1;
        }
        __syncthreads();
        if (kt + 1 < KT) LOADKT(kt + 1);

        bf8_t afh[4], afl[4], bfh[4], bfl[4];
#pragma unroll
        for (int i = 0; i < 4; i++) {
            int off = (wr * 64 + i * 16 + l15) * 40 + l4 * 8;
            afh[i] = *(const bf8_t*)&Ah[off];
            afl[i] = *(const bf8_t*)&Al[off];
        }
#pragma unroll
        for (int j = 0; j < 4; j++) {
            int off = (wc * 64 + j * 16 + l15) * 40 + l4 * 8;
            bfh[j] = *(const bf8_t*)&Bh[off];
            bfl[j] = *(const bf8_t*)&Bl[off];
        }
#pragma unroll
        for (int i = 0; i < 4; i++)
#pragma unroll
            for (int j = 0; j < 4; j++) {
                acc[i][j] = __builtin_amdgcn_mfma_f32_16x16x32_bf16(afh[i], bfh[j], acc[i][j], 0, 0, 0);
                acc[i][j] = __builtin_amdgcn_mfma_f32_16x16x32_bf16(afl[i], bfh[j], acc[i][j], 0, 0, 0);
                acc[i][j] = __builtin_amdgcn_mfma_f32_16x16x32_bf16(afh[i], bfl[j], acc[i][j], 0, 0, 0);
            }
    }
#undef LOADKT

#pragma unroll
    for (int j = 0; j < 4; j++) {
        int col = n0 + wc * 64 + j * 16 + l15;
        bool ok = !CHECK_N || (col < N);
        float bv = 0.f;
        if (bias && ok) bv = bias[col];
        if (ok) {
#pragma unroll
            for (int i = 0; i < 4; i++) {
                int rbase = m0 + wr * 64 + i * 16 + l4 * 4;
#pragma unroll
                for (int r = 0; r < 4; r++)
                    C[(size_t)(rbase + r) * ldc + col] = acc[i][j][r] + bv;
            }
        }
    }
}

// ---------------- dt prep ----------------
__global__ __launch_bounds__(256) void dt_k(
    const float* __restrict__ zx, const float* __restrict__ dt_bias,
    const float* __restrict__ A_log, float* __restrict__ dtp, float* __restrict__ dAb)
{
    int e = blockIdx.x * 256 + threadIdx.x;
    int l = e & 1023;
    int h = (e >> 10) & 31;
    int b = e >> 15;
    float dtr = zx[((size_t)b * L_ + l) * DINP_ + (DI_ + DXBC_) + h];
    float u = dtr + dt_bias[h];
    float sp = (u > 20.f) ? u : log1pf(__expf(u));
    float da = __expf(-__expf(A_log[h]) * sp);
    size_t o = ((size_t)b * H_ + h) * L_ + l;
    dtp[o] = sp;
    dAb[o] = da;
}

// ---------------- stash pre-conv boundary samples ----------------
__global__ __launch_bounds__(256) void stash_k(const float* __restrict__ zx, float* __restrict__ stash)
{
    int e = blockIdx.x * 256 + threadIdx.x;
    int c = e % DXBC_;
    int r = e / DXBC_;
    int k = r % 3;
    int bc = r / 3;
    int chunk = bc & 7;
    int b = bc >> 3;
    int t = chunk * 128 - 3 + k;
    float v = 0.f;
    if (t >= 0) v = zx[((size_t)b * L_ + t) * DINP_ + DI_ + c];
    stash[e] = v;
}

// ---------------- causal depthwise conv (K=4) + SiLU, in place ----------
__global__ __launch_bounds__(256) void conv_k(
    float* __restrict__ zx, const float* __restrict__ cw,
    const float* __restrict__ cb, const float* __restrict__ stash)
{
    int tid = threadIdx.x;
    int cblk = blockIdx.x;
    int chunk = blockIdx.y;
    int b = blockIdx.z;
    int c = cblk * 256 + tid;
    float4 w = *(const float4*)(cw + (size_t)c * 4);
    float bias = cb[c];
    const float* st = stash + ((size_t)(b * 8 + chunk) * 3) * DXBC_ + c;
    float x0 = st[0], x1 = st[DXBC_], x2 = st[2 * DXBC_];
    int t0 = chunk * 128;
    size_t base = ((size_t)b * L_ + t0) * DINP_ + DI_ + c;
#pragma unroll 4
    for (int t = 0; t < 128; t++) {
        float xt = zx[base + (size_t)t * DINP_];
        float a = w.x * x0 + w.y * x1 + w.z * x2 + w.w * xt + bias;
        a = a / (1.f + __expf(-a));
        zx[base + (size_t)t * DINP_] = a;
        x0 = x1; x1 = x2; x2 = xt;
    }
}

// ------- SSM scan v5: LDS-staged 8-step chunks; B/C via per-lane gather + readlane ---
// block per (b,h); wave g owns n in [8g,8g+8), lane = p. Per chunk each wave does
// TWO per-lane ds_read_b32 (lane l holds B/C[tt=l>>3][nbase+(l&7)]) then extracts
// uniforms via compile-time readlane (VALU pipe) -- replaces 4 uniform b128
// broadcasts per step. bcs rows padded to 260 so the gather is <=2-way aliased.
__global__ __launch_bounds__(1024, 1) void scan_k(
    const float* __restrict__ zx, const float* __restrict__ dtp,
    const float* __restrict__ dAb, const float* __restrict__ Dp,
    float* __restrict__ ys)
{
    int bh = blockIdx.x;
    int b = bh >> 5, h = bh & 31;
    int tid = threadIdx.x;
    int lane = tid & 63;
    int gu = __builtin_amdgcn_readfirstlane(tid >> 6);
    int nbase = gu * 8;
    __shared__ float ypart[8][16][64];
    __shared__ float bcs[8][260];        // cols 0..255 used; pad breaks bank alias
    __shared__ float xss[8][64];
    __shared__ float dtda[2][8];
    float hreg[8];
#pragma unroll
    for (int j = 0; j < 8; j++) hreg[j] = 0.f;
    float Dh = Dp[h];
    const float* dtrow = dtp + ((size_t)b * H_ + h) * L_;
    const float* darow = dAb + ((size_t)b * H_ + h) * L_;

    const int st_t = tid >> 7;
    const int st_j = (tid & 127) * 2;
    const int sx_t = tid >> 6;
    const int sx_ok = (sx_t < 8);
    const int gl_t = lane >> 3;          // gather row 0..7
    const int gl_j = lane & 7;           // gather n-offset 0..7

    {
        size_t row = ((size_t)b * L_ + st_t) * DINP_;
        float2 bc2 = *(const float2*)(zx + row + 2 * DI_ + st_j);
        *(float2*)&bcs[st_t][st_j] = bc2;
        if (sx_ok) {
            size_t rowx = ((size_t)b * L_ + sx_t) * DINP_;
            xss[sx_t][lane] = zx[rowx + DI_ + h * 64 + lane];
        }
        if (tid < 8)               dtda[0][tid] = dtrow[tid];
        else if (tid < 16)         dtda[1][tid - 8] = darow[tid - 8];
    }
    __syncthreads();

    float xout = 0.f;
    for (int c0 = 0; c0 < L_; c0 += 8) {
        // issue next chunk's loads (vector, vmcnt) into registers
        float2 nbc; float nx = 0.f, nd = 0.f;
        const bool pf = (c0 + 8) < L_;
        if (pf) {
            size_t row = ((size_t)b * L_ + c0 + 8 + st_t) * DINP_;
            nbc = *(const float2*)(zx + row + 2 * DI_ + st_j);
            if (sx_ok) {
                size_t rowx = ((size_t)b * L_ + c0 + 8 + sx_t) * DINP_;
                nx = zx[rowx + DI_ + h * 64 + lane];
            }
            if (tid < 8)       nd = dtrow[c0 + 8 + tid];
            else if (tid < 16) nd = darow[c0 + 8 + tid - 8];
        }
        // per-lane gather of this wave's whole-chunk B/C slice (2 x b32)
        float bvec = bcs[gl_t][nbase + gl_j];
        float cvec = bcs[gl_t][128 + nbase + gl_j];
#pragma unroll
        for (int tt = 0; tt < 8; ++tt) {
            float dtv = dtda[0][tt];
            float dav = dtda[1][tt];
            float xv  = xss[tt][lane];
            if (tt == gu) xout = xv;
            float u = dtv * xv;
            float ya = 0.f, yb = 0.f;
#pragma unroll
            for (int j = 0; j < 8; j += 2) {
                float bj0 = rdlane(bvec, tt * 8 + j);
                float cj0 = rdlane(cvec, tt * 8 + j);
                float bj1 = rdlane(bvec, tt * 8 + j + 1);
                float cj1 = rdlane(cvec, tt * 8 + j + 1);
                float t0 = u * bj0;
                float t1 = u * bj1;
                hreg[j]     = hreg[j]     * dav + t0; ya += hreg[j]     * cj0;
                hreg[j + 1] = hreg[j + 1] * dav + t1; yb += hreg[j + 1] * cj1;
            }
            ypart[tt][gu][lane] = ya + yb;
        }
        __syncthreads();
        if (gu < 8) {
            int t = c0 + gu;
            float v = 0.f;
#pragma unroll
            for (int w = 0; w < 16; w++) v += ypart[gu][w][lane];
            ys[((size_t)b * L_ + t) * DI_ + h * 64 + lane] = v + Dh * xout;
        }
        if (pf) {
            *(float2*)&bcs[st_t][st_j] = nbc;
            if (sx_ok) xss[sx_t][lane] = nx;
            if (tid < 8)       dtda[0][tid] = nd;
            else if (tid < 16) dtda[1][tid - 8] = nd;
        }
        __syncthreads();
    }
}

// ---------------- gating + RMSNorm, in place on ys ----------------
__global__ __launch_bounds__(256) void gate_norm_k(
    float* __restrict__ ys, const float* __restrict__ zx, const float* __restrict__ nw)
{
    int row = blockIdx.x;
    int tid = threadIdx.x;
    float* yr = ys + (size_t)row * DI_;
    const float* zr = zx + (size_t)row * DINP_;
    float4 v[2];
    float ss = 0.f;
#pragma unroll
    for (int i = 0; i < 2; i++) {
        int d = tid * 4 + i * 1024;
        float4 yv = *(const float4*)(yr + d);
        float4 zv = *(const float4*)(zr + d);
        v[i].x = yv.x * silu_f(zv.x);
        v[i].y = yv.y * silu_f(zv.y);
        v[i].z = yv.z * silu_f(zv.z);
        v[i].w = yv.w * silu_f(zv.w);
        ss += v[i].x * v[i].x + v[i].y * v[i].y + v[i].z * v[i].z + v[i].w * v[i].w;
    }
    __shared__ float red[256];
    red[tid] = ss;
    __syncthreads();
    for (int s = 128; s > 0; s >>= 1) {
        if (tid < s) red[tid] += red[tid + s];
        __syncthreads();
    }
    float scale = rsqrtf(red[0] / (float)DI_ + 1e-5f);
#pragma unroll
    for (int i = 0; i < 2; i++) {
        int d = tid * 4 + i * 1024;
        float4 nwv = *(const float4*)(nw + d);
        float4 o = make_float4(v[i].x * scale * nwv.x, v[i].y * scale * nwv.y,
                               v[i].z * scale * nwv.z, v[i].w * scale * nwv.w);
        *(float4*)(yr + d) = o;
    }
}

// ---------------- attention logits ----------------
__global__ __launch_bounds__(256) void attnw_k(
    const float* __restrict__ emb, const float* __restrict__ wat,
    const float* __restrict__ batn, float* __restrict__ logits)
{
    int row = blockIdx.x * 4 + (threadIdx.x >> 6);
    int lane = threadIdx.x & 63;
    const float* er = emb + (size_t)row * DM_;
    float s = 0.f;
#pragma unroll
    for (int k = 0; k < 16; k++) s += er[lane + k * 64] * wat[lane + k * 64];
#pragma unroll
    for (int off = 32; off; off >>= 1) s += __shfl_down(s, off);
    if (lane == 0) logits[row] = s + batn[0];
}

// ---------------- softmax over L per batch + zero pooled ----------------
__global__ __launch_bounds__(256) void softmax_k(
    const float* __restrict__ logits, float* __restrict__ wght, float* __restrict__ pooled)
{
    int b = blockIdx.x;
    int tid = threadIdx.x;
    __shared__ float red[256];
    float4 lv = *(const float4*)(logits + (size_t)b * L_ + tid * 4);
    float m = fmaxf(fmaxf(lv.x, lv.y), fmaxf(lv.z, lv.w));
    red[tid] = m;
    __syncthreads();
    for (int s = 128; s > 0; s >>= 1) {
        if (tid < s) red[tid] = fmaxf(red[tid], red[tid + s]);
        __syncthreads();
    }
    float bm = red[0];
    __syncthreads();
    float e0 = __expf(lv.x - bm), e1 = __expf(lv.y - bm);
    float e2 = __expf(lv.z - bm), e3 = __expf(lv.w - bm);
    red[tid] = e0 + e1 + e2 + e3;
    __syncthreads();
    for (int s = 128; s > 0; s >>= 1) {
        if (tid < s) red[tid] += red[tid + s];
        __syncthreads();
    }
    float inv = 1.f / red[0];
    *(float4*)(wght + (size_t)b * L_ + tid * 4) = make_float4(e0 * inv, e1 * inv, e2 * inv, e3 * inv);
    *(float4*)(pooled + (size_t)b * DM_ + tid * 4) = make_float4(0.f, 0.f, 0.f, 0.f);
}

// ---------------- weighted pooling ----------------
__global__ __launch_bounds__(256) void pool_k(
    const float* __restrict__ emb, const float* __restrict__ wght, float* __restrict__ pooled)
{
    int b = blockIdx.x, dc = blockIdx.y, lc = blockIdx.z;
    int d = dc * 256 + threadIdx.x;
    const float* wr = wght + (size_t)b * L_ + lc * 64;
    float acc = 0.f;
#pragma unroll 4
    for (int lt = 0; lt < 64; lt++)
        acc += emb[((size_t)(b * L_ + lc * 64 + lt)) * DM_ + d] * wr[lt];
    atomicAdd(pooled + (size_t)b * DM_ + d, acc);
}

// ---------------- final: out = pooled @ w_emb + b_emb ----------------
__global__ __launch_bounds__(256) void outp_k(
    const float* __restrict__ pooled, const float* __restrict__ wemb,
    const float* __restrict__ bemb, float* __restrict__ out)
{
    int ec = blockIdx.x, b = blockIdx.y;
    int tid = threadIdx.x;
    __shared__ float pl[DM_];
#pragma unroll
    for (int i = 0; i < 4; i++) pl[tid + i * 256] = pooled[(size_t)b * DM_ + tid + i * 256];
    __syncthreads();
    int e = ec * 256 + tid;
    float acc = bemb[e];
#pragma unroll 4
    for (int d = 0; d < DM_; d++) acc += pl[d] * wemb[(size_t)d * ED_ + e];
    out[(size_t)b * ED_ + e] = acc;
}

extern "C" void kernel_launch(void* const* d_in, const int* in_sizes, int n_in,
                              void* d_out, int out_size, void* d_ws, size_t ws_size,
                              hipStream_t stream)
{
    (void)in_sizes; (void)n_in; (void)out_size; (void)ws_size;
    const float* bert    = (const float*)d_in[0];
    const float* w_pb    = (const float*)d_in[1];
    const float* b_pb    = (const float*)d_in[2];
    const float* w_in    = (const float*)d_in[3];
    const float* conv_w  = (const float*)d_in[4];
    const float* conv_b  = (const float*)d_in[5];
    const float* dt_bias = (const float*)d_in[6];
    const float* A_log   = (const float*)d_in[7];
    const float* Dp      = (const float*)d_in[8];
    const float* norm_w  = (const float*)d_in[9];
    const float* w_outp  = (const float*)d_in[10];
    const float* w_attn  = (const float*)d_in[11];
    const float* b_attn  = (const float*)d_in[12];
    const float* w_emb   = (const float*)d_in[13];
    const float* b_emb   = (const float*)d_in[14];
    float* out = (float*)d_out;

    float* ws     = (float*)d_ws;
    float* zx     = ws;
    float* ys     = zx  + (size_t)8192 * 4384;
    float* xe     = ys  + (size_t)8192 * 2048;
    float* dtp    = xe  + (size_t)8192 * 1024;
    float* dAb    = dtp + 262144;
    float* stash  = dAb + 262144;
    float* logits = stash + 442368;
    float* wght   = logits + 8192;
    float* pooled = wght + 8192;

    size_t wpb_n = (size_t)8  * 32 * 4096;
    size_t win_n = (size_t)35 * 32 * 4096;
    size_t wop_n = (size_t)8  * 64 * 4096;
    unsigned short* wpb_h = (unsigned short*)ys;
    unsigned short* wpb_l = wpb_h + wpb_n;
    unsigned short* win_h = wpb_l + wpb_n;
    unsigned short* win_l = win_h + win_n;
    unsigned short* wop_h = (unsigned short*)zx;
    unsigned short* wop_l = wop_h + wop_n;

    convw_k<<<(unsigned)(((size_t)1024 * 1024 + 255) / 256), 256, 0, stream>>>(
        w_pb, wpb_h, wpb_l, 1024, 1024, 1024);
    convw_k<<<(unsigned)(((size_t)1024 * 4480 + 255) / 256), 256, 0, stream>>>(
        w_in, win_h, win_l, 1024, 4384, 4480);
    bgemm_k<false><<<dim3(8, 64), 256, 0, stream>>>(bert, wpb_h, wpb_l, xe, b_pb,
                                                    8192, 1024, 1024, 1024);
    bgemm_k<true><<<dim3(35, 64), 256, 0, stream>>>(xe, win_h, win_l, zx, nullptr,
                                                    8192, 4384, 1024, 4384);
    dt_k<<<1024, 256, 0, stream>>>(zx, dt_bias, A_log, dtp, dAb);
    stash_k<<<1728, 256, 0, stream>>>(zx, stash);
    conv_k<<<dim3(9, 8, 8), 256, 0, stream>>>(zx, conv_w, conv_b, stash);
    scan_k<<<256, 1024, 0, stream>>>(zx, dtp, dAb, Dp, ys);
    gate_norm_k<<<8192, 256, 0, stream>>>(ys, zx, norm_w);
    convw_k<<<(unsigned)(((size_t)2048 * 1024 + 255) / 256), 256, 0, stream>>>(
        w_outp, wop_h, wop_l, 2048, 1024, 1024);
    bgemm_k<false><<<dim3(8, 64), 256, 0, stream>>>(ys, wop_h, wop_l, xe, nullptr,
                                                    8192, 1024, 2048, 1024);
    attnw_k<<<2048, 256, 0, stream>>>(xe, w_attn, b_attn, logits);
    softmax_k<<<8, 256, 0, stream>>>(logits, wght, pooled);
    pool_k<<<dim3(8, 4, 16), 256, 0, stream>>>(xe, wght, pooled);
    outp_k<<<dim3(8, 8), 256, 0, stream>>>(pooled, w_emb, b_emb, out);
}

// Round 24
// 946.781 us; speedup vs baseline: 1.3033x; 1.3033x over previous
//
#include <hip/hip_runtime.h>
#include <hip/hip_bf16.h>
#include <math.h>

#define B_    8
#define L_    1024
#define DM_   1024
#define H_    32
#define P_    64
#define NS_   128
#define DI_   2048
#define DXBC_ 2304
#define DINP_ 4384
#define ED_   2048

typedef __attribute__((ext_vector_type(8))) short bf8_t;
typedef __attribute__((ext_vector_type(8))) unsigned short u16x8;
typedef __attribute__((ext_vector_type(4))) float f4_t;

__device__ __forceinline__ float silu_f(float x) { return x / (1.f + __expf(-x)); }

__device__ __forceinline__ unsigned short f2bf(float x) {
    unsigned u = __float_as_uint(x);
    unsigned r = u + 0x7fffu + ((u >> 16) & 1u);   // RNE
    return (unsigned short)(r >> 16);
}
__device__ __forceinline__ float bf2f(unsigned short h) {
    return __uint_as_float(((unsigned)h) << 16);
}

// ---------------- weight conversion: W[K][N] fp32 -> tiled Wt hi/lo bf16 ----------
__global__ __launch_bounds__(256) void convw_k(
    const float* __restrict__ W, unsigned short* __restrict__ hi,
    unsigned short* __restrict__ lo, int K, int N, int Npad)
{
    size_t e = (size_t)blockIdx.x * 256 + threadIdx.x;   // n fastest
    if (e >= (size_t)K * Npad) return;
    int n = (int)(e % Npad), k = (int)(e / Npad);
    float v = (n < N) ? W[(size_t)k * N + n] : 0.f;
    unsigned short h = f2bf(v);
    unsigned short l = f2bf(v - bf2f(h));
    int nt = n >> 7, r = n & 127, kt = k >> 5, c = k & 31;
    size_t dst = ((size_t)(nt * (K >> 5) + kt) << 12) + (r << 5) + c;
    hi[dst] = h; lo[dst] = l;
}

// ------- split-bf16 MFMA GEMM, fused fp32->bf16 A convert, depth-1 pipeline ------
template<bool CHECK_N>
__global__ __launch_bounds__(256, 2) void bgemm_k(
    const float* __restrict__ A, const unsigned short* __restrict__ Whi,
    const unsigned short* __restrict__ Wlo, float* __restrict__ C,
    const float* __restrict__ bias, int M, int N, int K, int ldc)
{
    __shared__ unsigned short Ah[128 * 40], Al[128 * 40];
    __shared__ unsigned short Bh[128 * 40], Bl[128 * 40];
    const int tid = threadIdx.x;
    const int m0 = blockIdx.y * 128, n0 = blockIdx.x * 128;
    const int lane = tid & 63;
    const int wv = tid >> 6;
    const int wr = wv >> 1, wc = wv & 1;
    const int l15 = lane & 15, l4 = lane >> 4;
    const int KT = K >> 5;

    f4_t acc[4][4];
#pragma unroll
    for (int i = 0; i < 4; i++)
#pragma unroll
        for (int j = 0; j < 4; j++) acc[i][j] = (f4_t){0.f, 0.f, 0.f, 0.f};

    const int ar = tid >> 2;
    const int ac = (tid & 3) * 8;
    const int trow = tid >> 1;
    const int tcol = (tid & 1) * 16;
    const int soff = trow * 40 + tcol;

    float4 a00, a01, a10, a11;
    u16x8 rWh0, rWh1, rWl0, rWl1;
#define LOADKT(KTI) {                                                               \
        const float* Ap0 = A + (size_t)(m0 + ar) * K + (KTI) * 32 + ac;             \
        const float* Ap1 = Ap0 + (size_t)64 * K;                                    \
        a00 = *(const float4*)Ap0; a01 = *(const float4*)(Ap0 + 4);                 \
        a10 = *(const float4*)Ap1; a11 = *(const float4*)(Ap1 + 4);                 \
        size_t woff = (((size_t)(blockIdx.x * KT + (KTI))) << 12) + (trow << 5) + tcol; \
        rWh0 = *(const u16x8*)(Whi + woff); rWh1 = *(const u16x8*)(Whi + woff + 8); \
        rWl0 = *(const u16x8*)(Wlo + woff); rWl1 = *(const u16x8*)(Wlo + woff + 8); }

    LOADKT(0);
    for (int kt = 0; kt < KT; ++kt) {
        __syncthreads();
        {
            float av0[8] = {a00.x, a00.y, a00.z, a00.w, a01.x, a01.y, a01.z, a01.w};
            float av1[8] = {a10.x, a10.y, a10.z, a10.w, a11.x, a11.y, a11.z, a11.w};
            u16x8 vh0, vl0, vh1, vl1;
#pragma unroll
            for (int j = 0; j < 8; j++) {
                unsigned short h0 = f2bf(av0[j]);
                vh0[j] = h0; vl0[j] = f2bf(av0[j] - bf2f(h0));
                unsigned short h1 = f2bf(av1[j]);
                vh1[j] = h1; vl1[j] = f2bf(av1[j] - bf2f(h1));
            }
            *(u16x8*)&Ah[ar * 40 + ac] = vh0;
            *(u16x8*)&Al[ar * 40 + ac] = vl0;
            *(u16x8*)&Ah[(ar + 64) * 40 + ac] = vh1;
            *(u16x8*)&Al[(ar + 64) * 40 + ac] = vl1;
            *(u16x8*)&Bh[soff]     = rWh0;
            *(u16x8*)&Bh[soff + 8] = rWh1;
            *(u16x8*)&Bl[soff]     = rWl0;
            *(u16x8*)&Bl[soff + 8] = rWl1;
        }
        __syncthreads();
        if (kt + 1 < KT) LOADKT(kt + 1);

        bf8_t afh[4], afl[4], bfh[4], bfl[4];
#pragma unroll
        for (int i = 0; i < 4; i++) {
            int off = (wr * 64 + i * 16 + l15) * 40 + l4 * 8;
            afh[i] = *(const bf8_t*)&Ah[off];
            afl[i] = *(const bf8_t*)&Al[off];
        }
#pragma unroll
        for (int j = 0; j < 4; j++) {
            int off = (wc * 64 + j * 16 + l15) * 40 + l4 * 8;
            bfh[j] = *(const bf8_t*)&Bh[off];
            bfl[j] = *(const bf8_t*)&Bl[off];
        }
#pragma unroll
        for (int i = 0; i < 4; i++)
#pragma unroll
            for (int j = 0; j < 4; j++) {
                acc[i][j] = __builtin_amdgcn_mfma_f32_16x16x32_bf16(afh[i], bfh[j], acc[i][j], 0, 0, 0);
                acc[i][j] = __builtin_amdgcn_mfma_f32_16x16x32_bf16(afl[i], bfh[j], acc[i][j], 0, 0, 0);
                acc[i][j] = __builtin_amdgcn_mfma_f32_16x16x32_bf16(afh[i], bfl[j], acc[i][j], 0, 0, 0);
            }
    }
#undef LOADKT

#pragma unroll
    for (int j = 0; j < 4; j++) {
        int col = n0 + wc * 64 + j * 16 + l15;
        bool ok = !CHECK_N || (col < N);
        float bv = 0.f;
        if (bias && ok) bv = bias[col];
        if (ok) {
#pragma unroll
            for (int i = 0; i < 4; i++) {
                int rbase = m0 + wr * 64 + i * 16 + l4 * 4;
#pragma unroll
                for (int r = 0; r < 4; r++)
                    C[(size_t)(rbase + r) * ldc + col] = acc[i][j][r] + bv;
            }
        }
    }
}

// ---------------- dt prep ----------------
__global__ __launch_bounds__(256) void dt_k(
    const float* __restrict__ zx, const float* __restrict__ dt_bias,
    const float* __restrict__ A_log, float* __restrict__ dtp, float* __restrict__ dAb)
{
    int e = blockIdx.x * 256 + threadIdx.x;
    int l = e & 1023;
    int h = (e >> 10) & 31;
    int b = e >> 15;
    float dtr = zx[((size_t)b * L_ + l) * DINP_ + (DI_ + DXBC_) + h];
    float u = dtr + dt_bias[h];
    float sp = (u > 20.f) ? u : log1pf(__expf(u));
    float da = __expf(-__expf(A_log[h]) * sp);
    size_t o = ((size_t)b * H_ + h) * L_ + l;
    dtp[o] = sp;
    dAb[o] = da;
}

// ---------------- stash pre-conv boundary samples ----------------
__global__ __launch_bounds__(256) void stash_k(const float* __restrict__ zx, float* __restrict__ stash)
{
    int e = blockIdx.x * 256 + threadIdx.x;
    int c = e % DXBC_;
    int r = e / DXBC_;
    int k = r % 3;
    int bc = r / 3;
    int chunk = bc & 7;
    int b = bc >> 3;
    int t = chunk * 128 - 3 + k;
    float v = 0.f;
    if (t >= 0) v = zx[((size_t)b * L_ + t) * DINP_ + DI_ + c];
    stash[e] = v;
}

// ---------------- causal depthwise conv (K=4) + SiLU, in place ----------
__global__ __launch_bounds__(256) void conv_k(
    float* __restrict__ zx, const float* __restrict__ cw,
    const float* __restrict__ cb, const float* __restrict__ stash)
{
    int tid = threadIdx.x;
    int cblk = blockIdx.x;
    int chunk = blockIdx.y;
    int b = blockIdx.z;
    int c = cblk * 256 + tid;
    float4 w = *(const float4*)(cw + (size_t)c * 4);
    float bias = cb[c];
    const float* st = stash + ((size_t)(b * 8 + chunk) * 3) * DXBC_ + c;
    float x0 = st[0], x1 = st[DXBC_], x2 = st[2 * DXBC_];
    int t0 = chunk * 128;
    size_t base = ((size_t)b * L_ + t0) * DINP_ + DI_ + c;
#pragma unroll 4
    for (int t = 0; t < 128; t++) {
        float xt = zx[base + (size_t)t * DINP_];
        float a = w.x * x0 + w.y * x1 + w.z * x2 + w.w * xt + bias;
        a = a / (1.f + __expf(-a));
        zx[base + (size_t)t * DINP_] = a;
        x0 = x1; x1 = x2; x2 = xt;
    }
}

// ------- SSM scan v6: LDS-staged 16-step chunks (R20 structure, chunk doubled) -----
// block per (b,h); wave g owns n in [8g,8g+8), lane = p. Uniform b128 broadcasts
// for B/C (proven free); halved barrier/staging/output-phase count vs chunk=8;
// output phase uses all 16 waves; prefetch distance 16 steps.
__global__ __launch_bounds__(1024, 1) void scan_k(
    const float* __restrict__ zx, const float* __restrict__ dtp,
    const float* __restrict__ dAb, const float* __restrict__ Dp,
    float* __restrict__ ys)
{
    int bh = blockIdx.x;
    int b = bh >> 5, h = bh & 31;
    int tid = threadIdx.x;
    int lane = tid & 63;
    int gu = __builtin_amdgcn_readfirstlane(tid >> 6);   // 0..15
    int nbase = gu * 8;
    __shared__ float ypart[16][16][64];   // 64 KB
    __shared__ float bcs[16][260];        // 16.6 KB (cols 0..255 used)
    __shared__ float xss[16][64];         // 4 KB
    __shared__ float dtda[2][16];
    float hreg[8];
#pragma unroll
    for (int j = 0; j < 8; j++) hreg[j] = 0.f;
    float Dh = Dp[h];
    const float* dtrow = dtp + ((size_t)b * H_ + h) * L_;
    const float* darow = dAb + ((size_t)b * H_ + h) * L_;

    const int st_t = tid >> 6;           // 0..15 (staging row)
    const int st_j = (tid & 63) * 4;     // 0..252 (float4 col)

    {
        size_t row = ((size_t)b * L_ + st_t) * DINP_;
        float4 bc4 = *(const float4*)(zx + row + 2 * DI_ + st_j);
        *(float4*)&bcs[st_t][st_j] = bc4;
        xss[st_t][lane] = zx[row + DI_ + h * 64 + lane];
        if (tid < 16)              dtda[0][tid] = dtrow[tid];
        else if (tid < 32)         dtda[1][tid - 16] = darow[tid - 16];
    }
    __syncthreads();

    float xout = 0.f;
    for (int c0 = 0; c0 < L_; c0 += 16) {
        // issue next chunk's loads (vector, vmcnt) into registers
        float4 nbc; float nx = 0.f, nd = 0.f;
        const bool pf = (c0 + 16) < L_;
        if (pf) {
            size_t row = ((size_t)b * L_ + c0 + 16 + st_t) * DINP_;
            nbc = *(const float4*)(zx + row + 2 * DI_ + st_j);
            nx = zx[row + DI_ + h * 64 + lane];
            if (tid < 16)      nd = dtrow[c0 + 16 + tid];
            else if (tid < 32) nd = darow[c0 + 16 + tid - 16];
        }
#pragma unroll
        for (int tt = 0; tt < 16; ++tt) {
            float dtv = dtda[0][tt];
            float dav = dtda[1][tt];
            float xv  = xss[tt][lane];
            if (tt == gu) xout = xv;
            float4 b0  = *(const float4*)&bcs[tt][nbase];
            float4 b1  = *(const float4*)&bcs[tt][nbase + 4];
            float4 cv0 = *(const float4*)&bcs[tt][128 + nbase];
            float4 cv1 = *(const float4*)&bcs[tt][128 + nbase + 4];
            float u = dtv * xv;
            float ya = 0.f, yb = 0.f;
            hreg[0] = hreg[0] * dav + u * b0.x; ya += hreg[0] * cv0.x;
            hreg[1] = hreg[1] * dav + u * b0.y; yb += hreg[1] * cv0.y;
            hreg[2] = hreg[2] * dav + u * b0.z; ya += hreg[2] * cv0.z;
            hreg[3] = hreg[3] * dav + u * b0.w; yb += hreg[3] * cv0.w;
            hreg[4] = hreg[4] * dav + u * b1.x; ya += hreg[4] * cv1.x;
            hreg[5] = hreg[5] * dav + u * b1.y; yb += hreg[5] * cv1.y;
            hreg[6] = hreg[6] * dav + u * b1.z; ya += hreg[6] * cv1.z;
            hreg[7] = hreg[7] * dav + u * b1.w; yb += hreg[7] * cv1.w;
            ypart[tt][gu][lane] = ya + yb;
        }
        __syncthreads();
        {
            int t = c0 + gu;                 // all 16 waves active
            float v = 0.f;
#pragma unroll
            for (int w = 0; w < 16; w++) v += ypart[gu][w][lane];
            ys[((size_t)b * L_ + t) * DI_ + h * 64 + lane] = v + Dh * xout;
        }
        if (pf) {
            *(float4*)&bcs[st_t][st_j] = nbc;
            xss[st_t][lane] = nx;
            if (tid < 16)      dtda[0][tid] = nd;
            else if (tid < 32) dtda[1][tid - 16] = nd;
        }
        __syncthreads();
    }
}

// ---------------- gating + RMSNorm, in place on ys ----------------
__global__ __launch_bounds__(256) void gate_norm_k(
    float* __restrict__ ys, const float* __restrict__ zx, const float* __restrict__ nw)
{
    int row = blockIdx.x;
    int tid = threadIdx.x;
    float* yr = ys + (size_t)row * DI_;
    const float* zr = zx + (size_t)row * DINP_;
    float4 v[2];
    float ss = 0.f;
#pragma unroll
    for (int i = 0; i < 2; i++) {
        int d = tid * 4 + i * 1024;
        float4 yv = *(const float4*)(yr + d);
        float4 zv = *(const float4*)(zr + d);
        v[i].x = yv.x * silu_f(zv.x);
        v[i].y = yv.y * silu_f(zv.y);
        v[i].z = yv.z * silu_f(zv.z);
        v[i].w = yv.w * silu_f(zv.w);
        ss += v[i].x * v[i].x + v[i].y * v[i].y + v[i].z * v[i].z + v[i].w * v[i].w;
    }
    __shared__ float red[256];
    red[tid] = ss;
    __syncthreads();
    for (int s = 128; s > 0; s >>= 1) {
        if (tid < s) red[tid] += red[tid + s];
        __syncthreads();
    }
    float scale = rsqrtf(red[0] / (float)DI_ + 1e-5f);
#pragma unroll
    for (int i = 0; i < 2; i++) {
        int d = tid * 4 + i * 1024;
        float4 nwv = *(const float4*)(nw + d);
        float4 o = make_float4(v[i].x * scale * nwv.x, v[i].y * scale * nwv.y,
                               v[i].z * scale * nwv.z, v[i].w * scale * nwv.w);
        *(float4*)(yr + d) = o;
    }
}

// ---------------- attention logits ----------------
__global__ __launch_bounds__(256) void attnw_k(
    const float* __restrict__ emb, const float* __restrict__ wat,
    const float* __restrict__ batn, float* __restrict__ logits)
{
    int row = blockIdx.x * 4 + (threadIdx.x >> 6);
    int lane = threadIdx.x & 63;
    const float* er = emb + (size_t)row * DM_;
    float s = 0.f;
#pragma unroll
    for (int k = 0; k < 16; k++) s += er[lane + k * 64] * wat[lane + k * 64];
#pragma unroll
    for (int off = 32; off; off >>= 1) s += __shfl_down(s, off);
    if (lane == 0) logits[row] = s + batn[0];
}

// ---------------- softmax over L per batch + zero pooled ----------------
__global__ __launch_bounds__(256) void softmax_k(
    const float* __restrict__ logits, float* __restrict__ wght, float* __restrict__ pooled)
{
    int b = blockIdx.x;
    int tid = threadIdx.x;
    __shared__ float red[256];
    float4 lv = *(const float4*)(logits + (size_t)b * L_ + tid * 4);
    float m = fmaxf(fmaxf(lv.x, lv.y), fmaxf(lv.z, lv.w));
    red[tid] = m;
    __syncthreads();
    for (int s = 128; s > 0; s >>= 1) {
        if (tid < s) red[tid] = fmaxf(red[tid], red[tid + s]);
        __syncthreads();
    }
    float bm = red[0];
    __syncthreads();
    float e0 = __expf(lv.x - bm), e1 = __expf(lv.y - bm);
    float e2 = __expf(lv.z - bm), e3 = __expf(lv.w - bm);
    red[tid] = e0 + e1 + e2 + e3;
    __syncthreads();
    for (int s = 128; s > 0; s >>= 1) {
        if (tid < s) red[tid] += red[tid + s];
        __syncthreads();
    }
    float inv = 1.f / red[0];
    *(float4*)(wght + (size_t)b * L_ + tid * 4) = make_float4(e0 * inv, e1 * inv, e2 * inv, e3 * inv);
    *(float4*)(pooled + (size_t)b * DM_ + tid * 4) = make_float4(0.f, 0.f, 0.f, 0.f);
}

// ---------------- weighted pooling ----------------
__global__ __launch_bounds__(256) void pool_k(
    const float* __restrict__ emb, const float* __restrict__ wght, float* __restrict__ pooled)
{
    int b = blockIdx.x, dc = blockIdx.y, lc = blockIdx.z;
    int d = dc * 256 + threadIdx.x;
    const float* wr = wght + (size_t)b * L_ + lc * 64;
    float acc = 0.f;
#pragma unroll 4
    for (int lt = 0; lt < 64; lt++)
        acc += emb[((size_t)(b * L_ + lc * 64 + lt)) * DM_ + d] * wr[lt];
    atomicAdd(pooled + (size_t)b * DM_ + d, acc);
}

// ---------------- final: out = pooled @ w_emb + b_emb ----------------
__global__ __launch_bounds__(256) void outp_k(
    const float* __restrict__ pooled, const float* __restrict__ wemb,
    const float* __restrict__ bemb, float* __restrict__ out)
{
    int ec = blockIdx.x, b = blockIdx.y;
    int tid = threadIdx.x;
    __shared__ float pl[DM_];
#pragma unroll
    for (int i = 0; i < 4; i++) pl[tid + i * 256] = pooled[(size_t)b * DM_ + tid + i * 256];
    __syncthreads();
    int e = ec * 256 + tid;
    float acc = bemb[e];
#pragma unroll 4
    for (int d = 0; d < DM_; d++) acc += pl[d] * wemb[(size_t)d * ED_ + e];
    out[(size_t)b * ED_ + e] = acc;
}

extern "C" void kernel_launch(void* const* d_in, const int* in_sizes, int n_in,
                              void* d_out, int out_size, void* d_ws, size_t ws_size,
                              hipStream_t stream)
{
    (void)in_sizes; (void)n_in; (void)out_size; (void)ws_size;
    const float* bert    = (const float*)d_in[0];
    const float* w_pb    = (const float*)d_in[1];
    const float* b_pb    = (const float*)d_in[2];
    const float* w_in    = (const float*)d_in[3];
    const float* conv_w  = (const float*)d_in[4];
    const float* conv_b  = (const float*)d_in[5];
    const float* dt_bias = (const float*)d_in[6];
    const float* A_log   = (const float*)d_in[7];
    const float* Dp      = (const float*)d_in[8];
    const float* norm_w  = (const float*)d_in[9];
    const float* w_outp  = (const float*)d_in[10];
    const float* w_attn  = (const float*)d_in[11];
    const float* b_attn  = (const float*)d_in[12];
    const float* w_emb   = (const float*)d_in[13];
    const float* b_emb   = (const float*)d_in[14];
    float* out = (float*)d_out;

    float* ws     = (float*)d_ws;
    float* zx     = ws;
    float* ys     = zx  + (size_t)8192 * 4384;
    float* xe     = ys  + (size_t)8192 * 2048;
    float* dtp    = xe  + (size_t)8192 * 1024;
    float* dAb    = dtp + 262144;
    float* stash  = dAb + 262144;
    float* logits = stash + 442368;
    float* wght   = logits + 8192;
    float* pooled = wght + 8192;

    size_t wpb_n = (size_t)8  * 32 * 4096;
    size_t win_n = (size_t)35 * 32 * 4096;
    size_t wop_n = (size_t)8  * 64 * 4096;
    unsigned short* wpb_h = (unsigned short*)ys;
    unsigned short* wpb_l = wpb_h + wpb_n;
    unsigned short* win_h = wpb_l + wpb_n;
    unsigned short* win_l = win_h + win_n;
    unsigned short* wop_h = (unsigned short*)zx;
    unsigned short* wop_l = wop_h + wop_n;

    convw_k<<<(unsigned)(((size_t)1024 * 1024 + 255) / 256), 256, 0, stream>>>(
        w_pb, wpb_h, wpb_l, 1024, 1024, 1024);
    convw_k<<<(unsigned)(((size_t)1024 * 4480 + 255) / 256), 256, 0, stream>>>(
        w_in, win_h, win_l, 1024, 4384, 4480);
    bgemm_k<false><<<dim3(8, 64), 256, 0, stream>>>(bert, wpb_h, wpb_l, xe, b_pb,
                                                    8192, 1024, 1024, 1024);
    bgemm_k<true><<<dim3(35, 64), 256, 0, stream>>>(xe, win_h, win_l, zx, nullptr,
                                                    8192, 4384, 1024, 4384);
    dt_k<<<1024, 256, 0, stream>>>(zx, dt_bias, A_log, dtp, dAb);
    stash_k<<<1728, 256, 0, stream>>>(zx, stash);
    conv_k<<<dim3(9, 8, 8), 256, 0, stream>>>(zx, conv_w, conv_b, stash);
    scan_k<<<256, 1024, 0, stream>>>(zx, dtp, dAb, Dp, ys);
    gate_norm_k<<<8192, 256, 0, stream>>>(ys, zx, norm_w);
    convw_k<<<(unsigned)(((size_t)2048 * 1024 + 255) / 256), 256, 0, stream>>>(
        w_outp, wop_h, wop_l, 2048, 1024, 1024);
    bgemm_k<false><<<dim3(8, 64), 256, 0, stream>>>(ys, wop_h, wop_l, xe, nullptr,
                                                    8192, 1024, 2048, 1024);
    attnw_k<<<2048, 256, 0, stream>>>(xe, w_attn, b_attn, logits);
    softmax_k<<<8, 256, 0, stream>>>(logits, wght, pooled);
    pool_k<<<dim3(8, 4, 16), 256, 0, stream>>>(xe, wght, pooled);
    outp_k<<<dim3(8, 8), 256, 0, stream>>>(pooled, w_emb, b_emb, out);
}